// Round 4
// baseline (467.025 us; speedup 1.0000x reference)
//
#include <hip/hip_runtime.h>

// RSSM rollout: B=16384 rows, T=64 sequential steps.
// Round-7: OCCUPANCY. Rounds 4-6 removed barriers and made the T-loop
// load-free; combined gain was only ~8% -- the step still costs ~13k cycles
// vs ~1.3k of issue+dep arithmetic. Diagnosis: grid was 1024 single-wave
// blocks = 1 wave/SIMD chip-wide; ALL latency (LDS ~120cy round trips, MFMA
// result latency, transcendental chains) fully exposed, nothing co-resident.
// Fix: each wave now owns 4 batch rows (A-rows 4..15 of the 16x16 MFMA are
// zero; garbage stays row-confined since C[m] depends only on A-row m).
// 4096 waves = 4 waves/SIMD (VGPR ~110 <= 128 budget). MFMA is 4x redundant
// but MFMA is ~5% of the step. Blocks = 128 threads = 2 fully independent
// waves (separate LDS slices, no __syncthreads anywhere). LDS/wave ~7.5 KB
// -> 16 waves/CU fits. Epilogue: one pointer + immediate offsets, 16-lane
// active stores (64B each), softplus+stores stay off the feedback path.

#define NBATCH 16384
#define NSTEP  64
#define ROWS   4       // real batch rows per wave
#define U_STRIDE 72    // row: s[0,32) h[32,64) pad[64,72)
#define HID_STRIDE 40  // 32 + pad

typedef short bf16x8 __attribute__((ext_vector_type(8)));
typedef short bf16x4 __attribute__((ext_vector_type(4)));
typedef float f32x4  __attribute__((ext_vector_type(4)));

__device__ __forceinline__ short f2bf(float f) {  // RNE fp32 -> bf16
    union { float f; unsigned int u; } c; c.f = f;
    unsigned int r = c.u + 0x7fffu + ((c.u >> 16) & 1u);
    return (short)(r >> 16);
}

__global__ __launch_bounds__(128, 4) void rssm_kernel(
    const float* __restrict__ s0, const float* __restrict__ h0,
    const float* __restrict__ actions,
    const float* __restrict__ W_ih, const float* __restrict__ W_hh,
    const float* __restrict__ b_ih, const float* __restrict__ b_hh,
    const float* __restrict__ fc1_w, const float* __restrict__ fc1_b,
    const float* __restrict__ mean_w, const float* __restrict__ mean_b,
    const float* __restrict__ std_w, const float* __restrict__ std_b,
    float* __restrict__ out)
{
    __shared__ alignas(16) short u_lds[2][16 * U_STRIDE];
    __shared__ alignas(16) short act_lds[2][NSTEP * ROWS * 8];  // [t][row][8]
    __shared__ alignas(16) short hid_lds[2][16 * HID_STRIDE];

    const int tid  = threadIdx.x;
    const int wid  = tid >> 6;         // wave in block (0/1), independent work
    const int lane = tid & 63;
    const int n    = lane & 15;
    const int q    = lane >> 4;
    const int base = (blockIdx.x * 2 + wid) * ROWS;   // 4 rows per wave

    short* __restrict__ u   = u_lds[wid];
    short* __restrict__ act = act_lds[wid];
    short* __restrict__ hid = hid_lds[wid];

    // ---- weight B-fragments. k-layout: [s(0..31) | h(32..63) | a(64..71) | 0]
    // B[k][col] = W[col][k], col = hf*16+n, k = c*32 + q*8 + j
    bf16x8 wb[2][3], fw[2], mw[2], sw[2];
    #pragma unroll
    for (int hf = 0; hf < 2; ++hf) {
        const int col = hf * 16 + n;
        #pragma unroll
        for (int c = 0; c < 3; ++c)
            #pragma unroll
            for (int j = 0; j < 8; ++j) {
                const int kk = q * 8 + j;                        // 0..31 in slice
                float w = 0.f;
                if (c == 0)              w = W_ih[col * 40 + kk];       // s part
                else if (c == 1)         w = W_hh[col * 32 + kk];       // h part
                else if (kk < 8)         w = W_ih[col * 40 + 32 + kk];  // a part
                wb[hf][c][j] = f2bf(w);
            }
        #pragma unroll
        for (int j = 0; j < 8; ++j) {
            const int k = q * 8 + j;
            fw[hf][j] = f2bf(fc1_w [col * 32 + k]);
            mw[hf][j] = f2bf(mean_w[col * 32 + k]);
            sw[hf][j] = f2bf(std_w [col * 32 + k]);
        }
    }
    float bc[2], fb[2], mb[2], sb[2];
    #pragma unroll
    for (int hf = 0; hf < 2; ++hf) {
        const int col = hf * 16 + n;
        bc[hf] = b_ih[col] + b_hh[col];
        fb[hf] = fc1_b[col];
        mb[hf] = mean_b[col];
        sb[hf] = std_b[col];
    }

    // ---- zero u tile (rows 4..15 stay bias-driven & finite forever)
    for (int i = lane; i < 16 * U_STRIDE; i += 64) u[i] = 0;
    __builtin_amdgcn_wave_barrier();

    // ---- init real rows: s0/h0 (fp32 -> bf16). lane -> (row = lane>>4, 2 cols)
    {
        const int row = lane >> 4;
        const int c2  = (lane & 15) * 2;
        const size_t rb = (size_t)(base + row) * 32 + c2;
        u[row * U_STRIDE + c2]          = f2bf(s0[rb]);
        u[row * U_STRIDE + c2 + 1]      = f2bf(s0[rb + 1]);
        u[row * U_STRIDE + 32 + c2]     = f2bf(h0[rb]);
        u[row * U_STRIDE + 32 + c2 + 1] = f2bf(h0[rb + 1]);
    }

    // ---- stage this wave's actions to LDS as bf16: act[t][row][8]
    // 4 rows x 64 t x 8 = 512 f32x4-chunks; 8 per lane, fully coalesced.
    #pragma unroll
    for (int it = 0; it < 8; ++it) {
        const int flat = it * 64 + lane;     // 0..511
        const int row  = flat >> 7;          // 128 chunks per row
        const int rem  = flat & 127;
        const int t    = rem >> 1;
        const int half = rem & 1;
        const f32x4 a4 = *(const f32x4*)(actions
            + (size_t)(base + row) * (NSTEP * 8) + t * 8 + half * 4);
        bf16x4 av;
        #pragma unroll
        for (int j = 0; j < 4; ++j) av[j] = f2bf(a4[j]);
        *(bf16x4*)(&act[(t * ROWS + row) * 8 + half * 4]) = av;
    }
    __builtin_amdgcn_wave_barrier();

    // ---- output base: q==0 lanes store rows base..base+3, col n (+imm offsets)
    float* op = out + (size_t)base * 64 + n;

    const bf16x8 zfrag = {0, 0, 0, 0, 0, 0, 0, 0};

    for (int t = 0; t < NSTEP; ++t) {
        // u A-frags: row = n, k = c*32 + q*8 + j
        bf16x8 ua0 = *(const bf16x8*)(&u[n * U_STRIDE + q * 8]);
        bf16x8 ua1 = *(const bf16x8*)(&u[n * U_STRIDE + 32 + q * 8]);
        bf16x8 af  = zfrag;
        if (q == 0 && n < ROWS) af = *(const bf16x8*)(&act[(t * ROWS + n) * 8]);

        f32x4 acc0 = {bc[0], bc[0], bc[0], bc[0]};
        f32x4 acc1 = {bc[1], bc[1], bc[1], bc[1]};
        acc0 = __builtin_amdgcn_mfma_f32_16x16x32_bf16(ua0, wb[0][0], acc0, 0, 0, 0);
        acc0 = __builtin_amdgcn_mfma_f32_16x16x32_bf16(ua1, wb[0][1], acc0, 0, 0, 0);
        acc0 = __builtin_amdgcn_mfma_f32_16x16x32_bf16(af,  wb[0][2], acc0, 0, 0, 0);
        acc1 = __builtin_amdgcn_mfma_f32_16x16x32_bf16(ua0, wb[1][0], acc1, 0, 0, 0);
        acc1 = __builtin_amdgcn_mfma_f32_16x16x32_bf16(ua1, wb[1][1], acc1, 0, 0, 0);
        acc1 = __builtin_amdgcn_mfma_f32_16x16x32_bf16(af,  wb[1][2], acc1, 0, 0, 0);

        // tanh -> h. C layout: row m = q*4+r, col = hf*16+n
        #pragma unroll
        for (int r = 0; r < 4; ++r) {
            const int m = q * 4 + r;
            float h0v = 1.f - 2.f / (__expf(2.f * acc0[r]) + 1.f);
            float h1v = 1.f - 2.f / (__expf(2.f * acc1[r]) + 1.f);
            u[m * U_STRIDE + 32 + n]      = f2bf(h0v);
            u[m * U_STRIDE + 32 + 16 + n] = f2bf(h1v);
        }
        __builtin_amdgcn_wave_barrier();

        bf16x8 ha = *(const bf16x8*)(&u[n * U_STRIDE + 32 + q * 8]);
        f32x4 f0 = {fb[0], fb[0], fb[0], fb[0]};
        f32x4 f1 = {fb[1], fb[1], fb[1], fb[1]};
        f0 = __builtin_amdgcn_mfma_f32_16x16x32_bf16(ha, fw[0], f0, 0, 0, 0);
        f1 = __builtin_amdgcn_mfma_f32_16x16x32_bf16(ha, fw[1], f1, 0, 0, 0);

        #pragma unroll
        for (int r = 0; r < 4; ++r) {
            const int m = q * 4 + r;
            float x0 = f0[r], x1 = f1[r];
            float e0 = x0 > 0.f ? x0 : (__expf(x0) - 1.f);
            float e1 = x1 > 0.f ? x1 : (__expf(x1) - 1.f);
            hid[m * HID_STRIDE + n]      = f2bf(e0);
            hid[m * HID_STRIDE + 16 + n] = f2bf(e1);
        }
        __builtin_amdgcn_wave_barrier();

        bf16x8 da = *(const bf16x8*)(&hid[n * HID_STRIDE + q * 8]);
        f32x4 m0 = {mb[0], mb[0], mb[0], mb[0]};
        f32x4 m1 = {mb[1], mb[1], mb[1], mb[1]};
        f32x4 v0 = {sb[0], sb[0], sb[0], sb[0]};
        f32x4 v1 = {sb[1], sb[1], sb[1], sb[1]};
        m0 = __builtin_amdgcn_mfma_f32_16x16x32_bf16(da, mw[0], m0, 0, 0, 0);
        m1 = __builtin_amdgcn_mfma_f32_16x16x32_bf16(da, mw[1], m1, 0, 0, 0);
        v0 = __builtin_amdgcn_mfma_f32_16x16x32_bf16(da, sw[0], v0, 0, 0, 0);
        v1 = __builtin_amdgcn_mfma_f32_16x16x32_bf16(da, sw[1], v1, 0, 0, 0);

        // critical path first: s_{t+1} = mean feedback into u s-section
        #pragma unroll
        for (int r = 0; r < 4; ++r) {
            const int m = q * 4 + r;
            u[m * U_STRIDE + n]      = f2bf(m0[r]);
            u[m * U_STRIDE + 16 + n] = f2bf(m1[r]);
        }
        __builtin_amdgcn_wave_barrier();

        // epilogue: q==0 lanes hold all 4 real rows (m = r). One base pointer,
        // 13-bit immediate offsets (max 960B). Stores never waited on.
        if (q == 0) {
            #pragma unroll
            for (int r = 0; r < 4; ++r) {
                float x0 = v0[r], x1 = v1[r];
                float sp0 = fmaxf(x0, 0.f) + __logf(1.f + __expf(-fabsf(x0)));
                float sp1 = fmaxf(x1, 0.f) + __logf(1.f + __expf(-fabsf(x1)));
                op[r * 64]      = m0[r];
                op[r * 64 + 16] = m1[r];
                op[r * 64 + 32] = sp0 + 1e-5f;
                op[r * 64 + 48] = sp1 + 1e-5f;
            }
        }
        op += (size_t)NBATCH * 64;
    }
}

extern "C" void kernel_launch(void* const* d_in, const int* in_sizes, int n_in,
                              void* d_out, int out_size, void* d_ws, size_t ws_size,
                              hipStream_t stream) {
    (void)in_sizes; (void)n_in; (void)out_size; (void)d_ws; (void)ws_size;
    rssm_kernel<<<dim3(NBATCH / (2 * ROWS)), dim3(128), 0, stream>>>(
        (const float*)d_in[0],  (const float*)d_in[1],  (const float*)d_in[2],
        (const float*)d_in[3],  (const float*)d_in[4],  (const float*)d_in[5],
        (const float*)d_in[6],  (const float*)d_in[7],  (const float*)d_in[8],
        (const float*)d_in[9],  (const float*)d_in[10], (const float*)d_in[11],
        (const float*)d_in[12], (float*)d_out);
}

// Round 6
// 379.280 us; speedup vs baseline: 1.2313x; 1.2313x over previous
//
#include <hip/hip_runtime.h>

// RSSM rollout: B=16384 rows, T=64 sequential steps.
// Round-9: ROWS=8 occupancy/VALU balance, with the round-3 PROVEN data path.
// Round-7 counters: ROWS=4 -> 230us, VALUBusy 85%, MfmaUtil 9.4% =
// VALU-issue-bound (4x row redundancy). ROWS=16 was ~170us latency-bound at
// 1 wave/SIMD. ROWS=8 -> 2048 waves = 2 waves/SIMD: half the per-row VALU of
// ROWS=4, still latency-hidden.
// Round-8's perm+cvt_pk rewrite FAILED (absmax 0.31): wave_barrier is
// IntrNoMem -- it does NOT order memory. Cross-lane LDS RAW (lane A writes,
// lane B reads) looks independent to the per-thread compiler, so loads with
// loop-invariant addresses can be hoisted past the writes. Fix here: every
// sync point = wave_barrier + asm volatile("" ::: "memory") (zero-cost
// compiler memory clobber); HW ordering is free (in-order DS pipe, 1 wave).
// Data path reverted to round-3's passing form (identity k-layout, f2bf
// short stores). Bias vectors are MFMA C-in (identical math, no per-step
// accumulator moves). T-loop remains globally load-free.

#define NBATCH 16384
#define NSTEP  64
#define ROWS   8       // real batch rows per wave
#define U_STRIDE 72    // row: s[0,32) h[32,64) pad[64,72)
#define HID_STRIDE 40  // 32 + pad

typedef short bf16x8 __attribute__((ext_vector_type(8)));
typedef short bf16x4 __attribute__((ext_vector_type(4)));
typedef float f32x4  __attribute__((ext_vector_type(4)));

#define WAVE_SYNC() do { \
    __builtin_amdgcn_wave_barrier(); \
    asm volatile("" ::: "memory"); \
} while (0)

__device__ __forceinline__ short f2bf(float f) {  // RNE fp32 -> bf16
    union { float f; unsigned int u; } c; c.f = f;
    unsigned int r = c.u + 0x7fffu + ((c.u >> 16) & 1u);
    return (short)(r >> 16);
}

__global__ __launch_bounds__(128, 2) void rssm_kernel(
    const float* __restrict__ s0, const float* __restrict__ h0,
    const float* __restrict__ actions,
    const float* __restrict__ W_ih, const float* __restrict__ W_hh,
    const float* __restrict__ b_ih, const float* __restrict__ b_hh,
    const float* __restrict__ fc1_w, const float* __restrict__ fc1_b,
    const float* __restrict__ mean_w, const float* __restrict__ mean_b,
    const float* __restrict__ std_w, const float* __restrict__ std_b,
    float* __restrict__ out)
{
    __shared__ alignas(16) short u_lds[2][16 * U_STRIDE];
    __shared__ alignas(16) short act_lds[2][NSTEP * ROWS * 8];  // [t][row][8]
    __shared__ alignas(16) short hid_lds[2][16 * HID_STRIDE];

    const int tid  = threadIdx.x;
    const int wid  = tid >> 6;         // wave in block (0/1), independent work
    const int lane = tid & 63;
    const int n    = lane & 15;
    const int q    = lane >> 4;
    const int base = (blockIdx.x * 2 + wid) * ROWS;   // 8 rows per wave

    short* u   = u_lds[wid];
    short* act = act_lds[wid];
    short* hid = hid_lds[wid];

    // ---- weight B-fragments. k-layout: [s(0..31) | h(32..63) | a(64..71) | 0]
    // B[k][col] = W[col][k], col = hf*16+n, k-slot kk = q*8+j
    bf16x8 wb[2][3], fw[2], mw[2], sw[2];
    #pragma unroll
    for (int hf = 0; hf < 2; ++hf) {
        const int col = hf * 16 + n;
        #pragma unroll
        for (int c = 0; c < 3; ++c)
            #pragma unroll
            for (int j = 0; j < 8; ++j) {
                const int kk = q * 8 + j;            // 0..31 within slice
                float w = 0.f;
                if (c == 0)      w = W_ih[col * 40 + kk];        // s part
                else if (c == 1) w = W_hh[col * 32 + kk];        // h part
                else if (kk < 8) w = W_ih[col * 40 + 32 + kk];   // a part
                wb[hf][c][j] = f2bf(w);
            }
        #pragma unroll
        for (int j = 0; j < 8; ++j) {
            const int k = q * 8 + j;
            fw[hf][j] = f2bf(fc1_w [col * 32 + k]);
            mw[hf][j] = f2bf(mean_w[col * 32 + k]);
            sw[hf][j] = f2bf(std_w [col * 32 + k]);
        }
    }
    float bc_[2], fb_[2], mb_[2], sb_[2];
    #pragma unroll
    for (int hf = 0; hf < 2; ++hf) {
        const int col = hf * 16 + n;
        bc_[hf] = b_ih[col] + b_hh[col];
        fb_[hf] = fc1_b[col];
        mb_[hf] = mean_b[col];
        sb_[hf] = std_b[col];
    }
    // hoisted bias vectors: used directly as MFMA C-in
    const f32x4 bc0v = {bc_[0], bc_[0], bc_[0], bc_[0]};
    const f32x4 bc1v = {bc_[1], bc_[1], bc_[1], bc_[1]};
    const f32x4 fb0v = {fb_[0], fb_[0], fb_[0], fb_[0]};
    const f32x4 fb1v = {fb_[1], fb_[1], fb_[1], fb_[1]};
    const f32x4 mb0v = {mb_[0], mb_[0], mb_[0], mb_[0]};
    const f32x4 mb1v = {mb_[1], mb_[1], mb_[1], mb_[1]};
    const f32x4 sb0v = {sb_[0], sb_[0], sb_[0], sb_[0]};
    const f32x4 sb1v = {sb_[1], sb_[1], sb_[1], sb_[1]};

    // ---- zero u tile (rows 8..15 stay finite forever; pads zero)
    for (int i = lane; i < 16 * U_STRIDE; i += 64) u[i] = 0;
    WAVE_SYNC();

    // ---- init real rows 0..7: s0/h0 (fp32 -> bf16, identity cols)
    {
        const int row = lane >> 3;            // 0..7
        const int c0  = (lane & 7) * 4;       // 4 cols per lane
        #pragma unroll
        for (int cc = 0; cc < 4; ++cc) {
            const int col = c0 + cc;
            u[row * U_STRIDE + col]      = f2bf(s0[(size_t)(base + row) * 32 + col]);
            u[row * U_STRIDE + 32 + col] = f2bf(h0[(size_t)(base + row) * 32 + col]);
        }
    }

    // ---- stage this wave's actions to LDS as bf16: act[t][row][8]
    // 8 rows x 64 t x 2 chunks = 1024 f32x4 chunks; 16 per lane, coalesced.
    #pragma unroll
    for (int it = 0; it < 16; ++it) {
        const int flat = it * 64 + lane;     // 0..1023
        const int row  = flat >> 7;          // 128 chunks per row
        const int rem  = flat & 127;
        const int t    = rem >> 1;
        const int half = rem & 1;
        const f32x4 a4 = *(const f32x4*)(actions
            + (size_t)(base + row) * (NSTEP * 8) + t * 8 + half * 4);
        bf16x4 av;
        #pragma unroll
        for (int j = 0; j < 4; ++j) av[j] = f2bf(a4[j]);
        *(bf16x4*)(&act[(t * ROWS + row) * 8 + half * 4]) = av;
    }
    WAVE_SYNC();

    // ---- output base: q<2 lanes store rows base+q*4+r, col n (+imm offsets)
    float* op = out + ((size_t)base + q * 4) * 64 + n;

    const bf16x8 zfrag = {0, 0, 0, 0, 0, 0, 0, 0};

    for (int t = 0; t < NSTEP; ++t) {
        // u A-frags: row = n, k-slot = q*8+j
        bf16x8 ua0 = *(const bf16x8*)(&u[n * U_STRIDE + q * 8]);
        bf16x8 ua1 = *(const bf16x8*)(&u[n * U_STRIDE + 32 + q * 8]);
        bf16x8 af  = zfrag;
        if (q == 0 && n < ROWS) af = *(const bf16x8*)(&act[(t * ROWS + n) * 8]);

        f32x4 acc0 = __builtin_amdgcn_mfma_f32_16x16x32_bf16(ua0, wb[0][0], bc0v, 0, 0, 0);
        f32x4 acc1 = __builtin_amdgcn_mfma_f32_16x16x32_bf16(ua0, wb[1][0], bc1v, 0, 0, 0);
        acc0 = __builtin_amdgcn_mfma_f32_16x16x32_bf16(ua1, wb[0][1], acc0, 0, 0, 0);
        acc1 = __builtin_amdgcn_mfma_f32_16x16x32_bf16(ua1, wb[1][1], acc1, 0, 0, 0);
        acc0 = __builtin_amdgcn_mfma_f32_16x16x32_bf16(af,  wb[0][2], acc0, 0, 0, 0);
        acc1 = __builtin_amdgcn_mfma_f32_16x16x32_bf16(af,  wb[1][2], acc1, 0, 0, 0);

        // tanh -> h. C layout: row m = q*4+r, col = hf*16+n
        #pragma unroll
        for (int r = 0; r < 4; ++r) {
            const int m = q * 4 + r;
            float h0v = 1.f - 2.f / (__expf(2.f * acc0[r]) + 1.f);
            float h1v = 1.f - 2.f / (__expf(2.f * acc1[r]) + 1.f);
            u[m * U_STRIDE + 32 + n]      = f2bf(h0v);
            u[m * U_STRIDE + 32 + 16 + n] = f2bf(h1v);
        }
        WAVE_SYNC();

        bf16x8 ha = *(const bf16x8*)(&u[n * U_STRIDE + 32 + q * 8]);
        f32x4 f0 = __builtin_amdgcn_mfma_f32_16x16x32_bf16(ha, fw[0], fb0v, 0, 0, 0);
        f32x4 f1 = __builtin_amdgcn_mfma_f32_16x16x32_bf16(ha, fw[1], fb1v, 0, 0, 0);

        #pragma unroll
        for (int r = 0; r < 4; ++r) {
            const int m = q * 4 + r;
            float x0 = f0[r], x1 = f1[r];
            float e0 = x0 > 0.f ? x0 : (__expf(x0) - 1.f);
            float e1 = x1 > 0.f ? x1 : (__expf(x1) - 1.f);
            hid[m * HID_STRIDE + n]      = f2bf(e0);
            hid[m * HID_STRIDE + 16 + n] = f2bf(e1);
        }
        WAVE_SYNC();

        bf16x8 da = *(const bf16x8*)(&hid[n * HID_STRIDE + q * 8]);
        f32x4 m0 = __builtin_amdgcn_mfma_f32_16x16x32_bf16(da, mw[0], mb0v, 0, 0, 0);
        f32x4 m1 = __builtin_amdgcn_mfma_f32_16x16x32_bf16(da, mw[1], mb1v, 0, 0, 0);
        f32x4 v0 = __builtin_amdgcn_mfma_f32_16x16x32_bf16(da, sw[0], sb0v, 0, 0, 0);
        f32x4 v1 = __builtin_amdgcn_mfma_f32_16x16x32_bf16(da, sw[1], sb1v, 0, 0, 0);

        // critical path first: s_{t+1} = mean feedback into u s-section
        #pragma unroll
        for (int r = 0; r < 4; ++r) {
            const int m = q * 4 + r;
            u[m * U_STRIDE + n]      = f2bf(m0[r]);
            u[m * U_STRIDE + 16 + n] = f2bf(m1[r]);
        }
        WAVE_SYNC();

        // epilogue: rows 0..7 live on q<2 lanes. Stores fire-and-forget
        // (loop has no vmem loads -> never waited on).
        if (q < 2) {
            #pragma unroll
            for (int r = 0; r < 4; ++r) {
                float x0 = v0[r], x1 = v1[r];
                float sp0 = fmaxf(x0, 0.f) + __logf(1.f + __expf(-fabsf(x0)));
                float sp1 = fmaxf(x1, 0.f) + __logf(1.f + __expf(-fabsf(x1)));
                op[r * 64]      = m0[r];
                op[r * 64 + 16] = m1[r];
                op[r * 64 + 32] = sp0 + 1e-5f;
                op[r * 64 + 48] = sp1 + 1e-5f;
            }
        }
        op += (size_t)NBATCH * 64;
    }
}

extern "C" void kernel_launch(void* const* d_in, const int* in_sizes, int n_in,
                              void* d_out, int out_size, void* d_ws, size_t ws_size,
                              hipStream_t stream) {
    (void)in_sizes; (void)n_in; (void)out_size; (void)d_ws; (void)ws_size;
    rssm_kernel<<<dim3(NBATCH / (2 * ROWS)), dim3(128), 0, stream>>>(
        (const float*)d_in[0],  (const float*)d_in[1],  (const float*)d_in[2],
        (const float*)d_in[3],  (const float*)d_in[4],  (const float*)d_in[5],
        (const float*)d_in[6],  (const float*)d_in[7],  (const float*)d_in[8],
        (const float*)d_in[9],  (const float*)d_in[10], (const float*)d_in[11],
        (const float*)d_in[12], (float*)d_out);
}